// Round 18
// baseline (980.650 us; speedup 1.0000x reference)
//
#include <hip/hip_runtime.h>

// Problem constants: BATCH=16, N=128, D=128, N_STEPS=5, EPS=1e-10
#define EPSF 1e-10f

__device__ __forceinline__ float f4sel(float4 a, int cc) {
  float r = (cc == 0) ? a.x : a.y;
  r = (cc == 2) ? a.z : r;
  r = (cc == 3) ? a.w : r;
  return r;
}

__device__ __forceinline__ float dpp_quad_sum(float x) {
  // full sum within each 4-lane quad: quad_perm [1,0,3,2] then [2,3,0,1]
  x += __int_as_float(__builtin_amdgcn_update_dpp(
      0, __float_as_int(x), 0xB1, 0xf, 0xf, true));
  x += __int_as_float(__builtin_amdgcn_update_dpp(
      0, __float_as_int(x), 0x4E, 0xf, 0xf, true));
  return x;
}

__device__ __forceinline__ float dpp_red_sum64(float x) {
  // canonical GCN wave64 sum: accumulate into lane 63, broadcast via readlane
  x += __int_as_float(__builtin_amdgcn_update_dpp(0, __float_as_int(x), 0x111, 0xf, 0xf, true));
  x += __int_as_float(__builtin_amdgcn_update_dpp(0, __float_as_int(x), 0x112, 0xf, 0xf, true));
  x += __int_as_float(__builtin_amdgcn_update_dpp(0, __float_as_int(x), 0x114, 0xf, 0xe, true));
  x += __int_as_float(__builtin_amdgcn_update_dpp(0, __float_as_int(x), 0x118, 0xf, 0xc, true));
  x += __int_as_float(__builtin_amdgcn_update_dpp(0, __float_as_int(x), 0x142, 0xa, 0xf, true));
  x += __int_as_float(__builtin_amdgcn_update_dpp(0, __float_as_int(x), 0x143, 0xc, 0xf, true));
  return __int_as_float(__builtin_amdgcn_readlane(__float_as_int(x), 63));
}

// ============================ K1: Cayley bases ============================
// M = I + A, A = L - L^T (symmetric part = I, SPD => unpivoted GJ stable).
// U = 2*M^{-1} - I. A IN REGISTERS (r9); one barrier/step via ping-pong
// rowbuf/colbuf publications.
#define SWZ4(i, j4) ((i) * 32 + ((j4) ^ ((i) & 31)))
#define SWZF(i, j) (SWZ4((i), (j) >> 2) * 4 + ((j) & 3))

__global__ __launch_bounds__(512, 2) void k_cayley(const float* __restrict__ L,
                                                   float* __restrict__ bases) {
  extern __shared__ float4 sm4[];
  float4* M4  = sm4;                   // 4096 f4 = 64 KB
  float*  Mf  = (float*)M4;
  float4* rb0 = sm4 + 4096;            // rowbuf ping (32 f4)
  float4* rb1 = rb0 + 32;              // rowbuf pong
  float*  cb0 = (float*)(rb1 + 32);    // colbuf ping (128 f)
  float*  cb1 = cb0 + 128;             // colbuf pong
  const int n = blockIdx.x, t = threadIdx.x;
  const float* Ln = L + n * 16384;
  // load linear -> swizzled (coalesced global reads)
  for (int f = t; f < 4096; f += 512) {
    int i = f >> 5, j4 = f & 31;
    M4[SWZ4(i, j4)] = ((const float4*)Ln)[f];
  }
  __syncthreads();
  // antisymmetrize in place + unit diagonal
  for (int f = t; f < 16384; f += 512) {
    int i = f >> 7, j = f & 127;
    if (i < j) {
      int a = SWZF(i, j), b = SWZF(j, i);
      float va = Mf[a], vb = Mf[b];
      Mf[a] = va - vb;
      Mf[b] = vb - va;
    } else if (i == j) {
      Mf[SWZF(i, i)] = 1.0f;
    }
  }
  __syncthreads();
  const int i = t & 127;     // row owned by this thread
  const int h2 = t >> 7;     // which 8-f4 chunk of the row (0..3)
  // ---- pull own row slice into registers
  float4 Ar[8];
  #pragma unroll
  for (int u = 0; u < 8; ++u) Ar[u] = M4[SWZ4(i, h2 * 8 + u)];
  // ---- prologue publishes: row 0, column 0
  if (i == 0) {
    #pragma unroll
    for (int u = 0; u < 8; ++u) rb0[h2 * 8 + u] = Ar[u];
  }
  if (h2 == 0) cb0[i] = Ar[0].x;   // element (i, 0)
  __syncthreads();
  for (int k = 0; k < 128; ++k) {
    const float4* rbC = (k & 1) ? rb1 : rb0;
    float4*       rbN = (k & 1) ? rb0 : rb1;
    const float*  cbC = (k & 1) ? cb1 : cb0;
    float*        cbN = (k & 1) ? cb0 : cb1;
    const float pivinv = 1.0f / cbC[k];   // broadcast
    const float coef = cbC[i] * pivinv;   // own multiplier (coalesced)
    const int kj4 = k >> 2, kc = k & 3;
    const int nj4 = (k + 1) >> 2, ncc = (k + 1) & 3;
    const bool isPiv = (i == k);
    const bool isNext = (i == k + 1);
    float colv = 0.0f;
    #pragma unroll
    for (int u = 0; u < 8; ++u) {
      const int jj = h2 * 8 + u;
      float4 r = rbC[jj];   // broadcast read (uniform per wave)
      float4 a;
      if (isPiv) {          // scale pivot row; (k,k) -> pivinv
        a.x = r.x * pivinv; a.y = r.y * pivinv;
        a.z = r.z * pivinv; a.w = r.w * pivinv;
        if (jj == kj4) {
          a.x = (kc == 0) ? pivinv : a.x;
          a.y = (kc == 1) ? pivinv : a.y;
          a.z = (kc == 2) ? pivinv : a.z;
          a.w = (kc == 3) ? pivinv : a.w;
        }
      } else {              // eliminate; (i,k) -> -coef
        a = Ar[u];
        a.x -= coef * r.x; a.y -= coef * r.y;
        a.z -= coef * r.z; a.w -= coef * r.w;
        if (jj == kj4) {
          a.x = (kc == 0) ? -coef : a.x;
          a.y = (kc == 1) ? -coef : a.y;
          a.z = (kc == 2) ? -coef : a.z;
          a.w = (kc == 3) ? -coef : a.w;
        }
      }
      Ar[u] = a;
      if (jj == nj4) colv = f4sel(a, ncc);  // extract A[i][k+1]
      if (isNext) rbN[jj] = a;              // publish next pivot row
    }
    if (h2 == (nj4 >> 3)) cbN[i] = colv;    // publish next column (k<127)
    __syncthreads();
  }
  // ---- regs -> LDS, then U = 2*Minv - I coalesced writeout
  #pragma unroll
  for (int u = 0; u < 8; ++u) M4[SWZ4(i, h2 * 8 + u)] = Ar[u];
  __syncthreads();
  for (int f = t; f < 16384; f += 512) {
    int ii = f >> 7, j = f & 127;
    float v = Mf[SWZF(ii, j)];
    bases[n * 16384 + f] = 2.0f * v - ((ii == j) ? 1.0f : 0.0f);
  }
}

// ============================ K2a: Gram = B_flat B_flat^T (two-stage GEMM) ============================
__global__ __launch_bounds__(256) void k_gramp(const float* __restrict__ bases,
                                               float* __restrict__ part) {
  __shared__ __align__(16) float tile[64][132];
  const int b = blockIdx.x, t = threadIdx.x;
  const int tx = t & 15, ty = t >> 4;
  const int i0 = tx * 8, j0 = ty * 8;
  const int k0 = b * 512;
  float acc[8][8];
  #pragma unroll
  for (int u = 0; u < 8; ++u)
    #pragma unroll
    for (int v = 0; v < 8; ++v) acc[u][v] = 0.f;
  for (int c0 = 0; c0 < 512; c0 += 64) {
    __syncthreads();  // protect previous sub-chunk's reads
    for (int f = t; f < 8192; f += 256) {
      int i = f >> 6, kk = f & 63;
      tile[kk][i] = bases[i * 16384 + k0 + c0 + kk];
    }
    __syncthreads();
    for (int kk = 0; kk < 64; ++kk) {
      float4 a0 = *(const float4*)&tile[kk][i0];
      float4 a1 = *(const float4*)&tile[kk][i0 + 4];
      float4 b0 = *(const float4*)&tile[kk][j0];
      float4 b1 = *(const float4*)&tile[kk][j0 + 4];
      float av[8] = {a0.x, a0.y, a0.z, a0.w, a1.x, a1.y, a1.z, a1.w};
      float bv[8] = {b0.x, b0.y, b0.z, b0.w, b1.x, b1.y, b1.z, b1.w};
      #pragma unroll
      for (int u = 0; u < 8; ++u)
        #pragma unroll
        for (int v = 0; v < 8; ++v) acc[u][v] += av[u] * bv[v];
    }
  }
  float* P = part + b * 16384;
  #pragma unroll
  for (int u = 0; u < 8; ++u) {
    #pragma unroll
    for (int v4 = 0; v4 < 2; ++v4) {
      float4 o;
      o.x = acc[u][v4 * 4 + 0]; o.y = acc[u][v4 * 4 + 1];
      o.z = acc[u][v4 * 4 + 2]; o.w = acc[u][v4 * 4 + 3];
      *(float4*)&P[(i0 + u) * 128 + j0 + v4 * 4] = o;
    }
  }
}

// Stage 2: deterministic partial reduction (no atomics).
__global__ __launch_bounds__(256) void k_gsum(const float* __restrict__ part,
                                              float* __restrict__ G) {
  const int g = blockIdx.x * 256 + threadIdx.x;
  float s = 0.f;
  for (int p = 0; p < 32; ++p) s += part[p * 16384 + g];
  G[g] = s;
}

// ============================ K2b: tension + softmax + mask ============================
__global__ __launch_bounds__(128) void k_wsoft(const float* __restrict__ G,
                                               const float* __restrict__ temp_p,
                                               float* __restrict__ w,
                                               float* __restrict__ tension_out) {
  const int i = blockIdx.x, t = threadIdx.x;  // t = j
  __shared__ float rr[2], r2[2];
  float temp = fmaxf(fabsf(*temp_p), 0.01f);
  float gii = G[i * 128 + i], gjj = G[t * 128 + t], gij = G[i * 128 + t];
  float ten = sqrtf(fmaxf(gii + gjj - 2.0f * gij, 0.0f) + 1e-8f);
  tension_out[i * 128 + t] = ten;
  float logit = -ten / temp;
  float m = logit;
  for (int s = 32; s > 0; s >>= 1) m = fmaxf(m, __shfl_xor(m, s));
  if ((t & 63) == 0) rr[t >> 6] = m;
  __syncthreads();
  float mx = fmaxf(rr[0], rr[1]);
  float ex = expf(logit - mx);
  float ssum = ex;
  for (int s = 32; s > 0; s >>= 1) ssum += __shfl_xor(ssum, s);
  if ((t & 63) == 0) r2[t >> 6] = ssum;
  __syncthreads();
  float tot = r2[0] + r2[1];
  float wv = ex / tot;
  if (t == i) wv = 0.0f;
  w[i * 128 + t] = wv;
}

// ============================ K3: measurements + initial norms ============================
__global__ __launch_bounds__(128) void k_meas(const float* __restrict__ x,
                                              const float* __restrict__ bases,
                                              float* __restrict__ meas_out,
                                              float* __restrict__ state0,
                                              float* __restrict__ norms0) {
  const int n = blockIdx.x, t = threadIdx.x;  // t = k
  __shared__ float xs[2048];
  __shared__ float red[2];
  for (int f = t; f < 2048; f += 128) xs[f] = x[f];
  __syncthreads();
  float acc[16];
  #pragma unroll
  for (int b = 0; b < 16; ++b) acc[b] = 0.f;
  for (int d = 0; d < 128; ++d) {
    float u = bases[n * 16384 + d * 128 + t];  // coalesced over t
    #pragma unroll
    for (int b = 0; b < 16; ++b) acc[b] += xs[b * 128 + d] * u;
  }
  for (int b = 0; b < 16; ++b) {
    meas_out[(b * 128 + n) * 128 + t] = acc[b];
    state0[(b * 128 + n) * 128 + t] = acc[b];
  }
  for (int b = 0; b < 16; ++b) {
    float v = acc[b] * acc[b];
    for (int s = 32; s > 0; s >>= 1) v += __shfl_down(v, s);
    if ((t & 63) == 0) red[t >> 6] = v;
    __syncthreads();
    if (t == 0) norms0[b * 128 + n] = sqrtf(red[0] + red[1]);
    __syncthreads();
  }
}

// ============================ K4: one interaction step ============================
// r17: 3-phase / 4-barrier structure (was 4 chunks x 3 barriers = 12).
// Full batch state staged ONCE into XOR-swizzled LDS (66 KB dynamic).
// Phase 1: thread t owns dot(s_n, s_t) -- row-n broadcast x row-t
// conflict-free, NO cross-lane reductions. Phase 2: f4-broadcast c reads +
// 2-way-free scalar s reads. Distance via norm identity (r14b).
#define SSW(r, u) ((r) * 32 + ((u) ^ ((r) & 31)))

__global__ __launch_bounds__(128) void k_step(const float* __restrict__ src,
                                              float* __restrict__ dst,
                                              const float* __restrict__ w,
                                              const float* __restrict__ norms_in,
                                              float* __restrict__ norms_out,
                                              const float* __restrict__ tgt_p,
                                              const float* __restrict__ step_p) {
  extern __shared__ float sm[];
  float4* S4  = (float4*)sm;     // 4096 f4 swizzled
  float*  Sf  = sm;
  float*  cbuf = sm + 16384;     // 128
  float*  red2 = cbuf + 128;     // 2 (+pad)
  const int b = blockIdx.x >> 7, n = blockIdx.x & 127, t = threadIdx.x;
  const float target = *tgt_p;
  const float step = fminf(fmaxf(fabsf(*step_p), 0.001f), 0.5f);
  const float* srcb = src + b * 16384;
  // ---- stage all of S (swizzled, coalesced)
  for (int f = t; f < 4096; f += 128) {
    int r = f >> 5, u = f & 31;
    S4[SSW(r, u)] = ((const float4*)srcb)[f];
  }
  __syncthreads();  // B1
  // ---- phase 1: thread t computes dot(s_n, s_t); no reductions
  float dp = 0.f;
  #pragma unroll
  for (int u = 0; u < 32; ++u) {
    float4 a = S4[SSW(n, u)];    // broadcast (uniform addr)
    float4 m4 = S4[SSW(t, u)];   // conflict-free (XOR spread)
    dp += a.x * m4.x + a.y * m4.y + a.z * m4.z + a.w * m4.w;
  }
  float norm_n = norms_in[b * 128 + n];
  float norm_m = norms_in[b * 128 + t];
  float sq = norm_n * norm_n + norm_m * norm_m - 2.0f * dp;
  float cs = dp / ((norm_n + EPSF) * (norm_m + EPSF));
  float fm = (cs - target) * w[n * 128 + t];
  cbuf[t] = fm / (sqrtf(fmaxf(sq, 0.0f)) + EPSF);
  __syncthreads();  // B2
  // ---- phase 2: thread t = d; f_d = csum*x_d - sum_m c[m]*s[m][d]
  const int fq = t >> 2, fc = t & 3;
  float x_d = Sf[SSW(n, fq) * 4 + fc];
  float facc = 0.f, csum = 0.f;
  const float4* c4 = (const float4*)cbuf;
  #pragma unroll 4
  for (int m4 = 0; m4 < 32; ++m4) {
    float4 c = c4[m4];           // broadcast
    int m0 = m4 * 4;
    float s0v = Sf[SSW(m0 + 0, fq) * 4 + fc];
    float s1v = Sf[SSW(m0 + 1, fq) * 4 + fc];
    float s2v = Sf[SSW(m0 + 2, fq) * 4 + fc];
    float s3v = Sf[SSW(m0 + 3, fq) * 4 + fc];
    facc += c.x * s0v + c.y * s1v + c.z * s2v + c.w * s3v;
    csum += (c.x + c.y) + (c.z + c.w);
  }
  float nv = x_d + step * (csum * x_d - facc);
  dst[(b * 128 + n) * 128 + t] = nv;
  float v = nv * nv;
  for (int s = 32; s > 0; s >>= 1) v += __shfl_down(v, s);
  if ((t & 63) == 0) red2[t >> 6] = v;
  __syncthreads();  // B3
  if (t == 0) norms_out[b * 128 + n] = sqrtf(red2[0] + red2[1]);
}

// ============================ K5: expressions ============================
__global__ __launch_bounds__(128) void k_expr(const float* __restrict__ eq,
                                              const float* __restrict__ bases,
                                              float* __restrict__ expr_out) {
  const int n = blockIdx.x, t = threadIdx.x;  // t = k
  __shared__ __align__(16) float es[16][128];
  for (int f = t; f < 2048; f += 128)
    es[f >> 7][f & 127] = eq[((f >> 7) * 128 + n) * 128 + (f & 127)];
  __syncthreads();
  float acc[16];
  #pragma unroll
  for (int b = 0; b < 16; ++b) acc[b] = 0.f;
  const float4* U = (const float4*)(bases + n * 16384 + t * 128);
  for (int d4 = 0; d4 < 32; ++d4) {
    float4 u = U[d4];
    #pragma unroll
    for (int b = 0; b < 16; ++b) {
      float4 e4 = ((const float4*)&es[b][0])[d4];
      acc[b] += u.x * e4.x + u.y * e4.y + u.z * e4.z + u.w * e4.w;
    }
  }
  for (int b = 0; b < 16; ++b) expr_out[(b * 128 + n) * 128 + t] = acc[b];
}

// ============================ K5b: output_avg ============================
__global__ __launch_bounds__(128) void k_avg(const float* __restrict__ expr,
                                             float* __restrict__ avg) {
  const int b = blockIdx.x, t = threadIdx.x;
  float s = 0.f;
  for (int n = 0; n < 128; ++n) s += expr[(b * 128 + n) * 128 + t];
  avg[b * 128 + t] = s * (1.0f / 128.0f);
}

// ============================ K6: rho ============================
__global__ __launch_bounds__(256) void k_rho(const float* __restrict__ eq,
                                             const float* __restrict__ norms,
                                             float* __restrict__ rho) {
  const int b = blockIdx.x >> 3, dt = blockIdx.x & 7;
  const int t = threadIdx.x;
  __shared__ float ch[32][129];
  int e = t & 127, dl = t >> 7;
  float acc[8];
  #pragma unroll
  for (int o = 0; o < 8; ++o) acc[o] = 0.f;
  for (int c0 = 0; c0 < 128; c0 += 32) {
    for (int f = t; f < 4096; f += 256) {
      int row = f >> 7, col = f & 127;
      int nn = c0 + row;
      float inv = 1.0f / (norms[b * 128 + nn] + EPSF);
      ch[row][col] = eq[(b * 128 + nn) * 128 + col] * inv;
    }
    __syncthreads();
    for (int nn = 0; nn < 32; ++nn) {
      float me = ch[nn][e];
      #pragma unroll
      for (int o = 0; o < 8; ++o) {
        int d = dt * 16 + dl + o * 2;
        acc[o] += ch[nn][d] * me;
      }
    }
    __syncthreads();
  }
  for (int o = 0; o < 8; ++o) {
    int d = dt * 16 + dl + o * 2;
    rho[(b * 128 + d) * 128 + e] = acc[o] * (1.0f / 128.0f);
  }
}

// ============================ K7: Householder tridiagonalization ============================
// r14 champion (215 us), REVERTED from r16 replication (conflicts were off
// the critical path; replication only added overhead). 8 waves, quarter-rows
// of 8 f4 in regs, DPP reductions, ping-pong column buffer, 2 barriers/step.
// DO NOT TUNE FURTHER: r12 (regs+2w) and r16 (replication) both regressed.
__global__ __launch_bounds__(512, 1) void k_tridiag(const float* __restrict__ rho,
                                                    float* __restrict__ dvec_g,
                                                    float* __restrict__ evec_g) {
  __shared__ __align__(16) float cb0[128];
  __shared__ __align__(16) float cb1[128];
  __shared__ __align__(16) float pbuf[128];
  __shared__ float dvl[128], evl[128];
  __shared__ float redS[8], redK[8], redX[1];
  const int bb = blockIdx.x, t = threadIdx.x;
  const int i = t >> 2, h = t & 3, wv = t >> 6;
  const float* R = rho + bb * 16384;
  // ---- own quarter-row into registers (8 f4)
  float4 Ar[8];
  const float4* Rp = (const float4*)(R + i * 128 + h * 32);
  #pragma unroll
  for (int u = 0; u < 8; ++u) Ar[u] = Rp[u];
  // ---- prologue: column 0, sigma^2, x0, diag
  if (h == 0) {
    cb0[i] = (i == 0) ? 0.f : Ar[0].x;   // zeros at i<=k
    if (i == 0) dvl[0] = Ar[0].x;
    if (i == 1) redX[0] = Ar[0].x;
  }
  {
    float s2w = dpp_red_sum64((h == 0 && i > 0) ? Ar[0].x * Ar[0].x : 0.f);
    if ((t & 63) == 0) redS[wv] = s2w;
  }
  __syncthreads();
  for (int k = 0; k < 126; ++k) {
    const float* cbC = (k & 1) ? cb1 : cb0;   // column k (zeros at i<=k)
    float*       cbN = (k & 1) ? cb0 : cb1;   // column k+1
    // ---- uniform head
    float sig2 = redS[0] + redS[1] + redS[2] + redS[3] +
                 redS[4] + redS[5] + redS[6] + redS[7];
    float x0 = redX[0];
    const bool skip = (sig2 < 1e-30f);
    float sig = sqrtf(sig2);
    float alpha = (x0 >= 0.f) ? -sig : sig;
    if (skip) alpha = 0.f;
    float beta = skip ? 0.f : 1.f / (sig2 - alpha * x0);
    float w0 = x0 - alpha;
    if (t == 0) evl[k] = alpha;
    const int jn4 = (k + 1) >> 2, ncc = (k + 1) & 3, hn = (k + 1) >> 5;
    float vt = (i == k + 1) ? w0 : cbC[i];    // zeros for i<=k from buffer
    // ---- matvec p_i = beta * sum_j A[i][j] v[j] (quarter-split)
    const float4* cv4 = (const float4*)cbC;
    float pp = 0.f;
    #pragma unroll
    for (int u = 0; u < 8; ++u) {
      const int jj = h * 8 + u;
      float4 v = cv4[jj];
      if (jj == jn4) {
        v.x = (0 == ncc) ? w0 : v.x;
        v.y = (1 == ncc) ? w0 : v.y;
        v.z = (2 == ncc) ? w0 : v.z;
        v.w = (3 == ncc) ? w0 : v.w;
      }
      pp += Ar[u].x * v.x + Ar[u].y * v.y + Ar[u].z * v.z + Ar[u].w * v.w;
    }
    pp = dpp_quad_sum(pp);   // all 4 quarter-lanes hold the full row-dot
    float p = beta * pp;
    if (i <= k) p = 0.f;
    if (h == 0) pbuf[i] = p;
    float kpw = dpp_red_sum64((h == 0) ? vt * p : 0.f);
    if ((t & 63) == 0) redK[wv] = kpw;
    __syncthreads();  // S1: pbuf + redK visible
    float K = (redK[0] + redK[1] + redK[2] + redK[3] +
               redK[4] + redK[5] + redK[6] + redK[7]) * beta * 0.5f;
    // ---- rank-2 update in registers + extract column k+1
    float cn = 0.f;
    if (i > k) {
      float qt = p - K * vt;
      const float4* pv4 = (const float4*)pbuf;
      #pragma unroll
      for (int u = 0; u < 8; ++u) {
        const int jj = h * 8 + u;
        float4 v = cv4[jj];
        if (jj == jn4) {
          v.x = (0 == ncc) ? w0 : v.x;
          v.y = (1 == ncc) ? w0 : v.y;
          v.z = (2 == ncc) ? w0 : v.z;
          v.w = (3 == ncc) ? w0 : v.w;
        }
        float4 pq = pv4[jj];
        float qx = pq.x - K * v.x, qy = pq.y - K * v.y;
        float qz = pq.z - K * v.z, qw = pq.w - K * v.w;
        Ar[u].x -= vt * qx + qt * v.x;
        Ar[u].y -= vt * qy + qt * v.y;
        Ar[u].z -= vt * qz + qt * v.z;
        Ar[u].w -= vt * qw + qt * v.w;
        if (jj == jn4) cn = f4sel(Ar[u], ncc);
      }
    }
    // ---- publish next-step state (quarter hn owns column k+1)
    if (h == hn) cbN[i] = (i <= k + 1) ? 0.f : cn;
    if (i == k + 1 && h == hn) dvl[k + 1] = cn;
    if (i == k + 2 && h == hn) redX[0] = cn;
    float s2w = dpp_red_sum64((h == hn && i > k + 1) ? cn * cn : 0.f);
    if ((t & 63) == 0) redS[wv] = s2w;
    __syncthreads();  // S2
  }
  // ---- epilogue from registers
  if (i == 126 && h == 3) dvl[126] = Ar[7].z;
  if (i == 127 && h == 3) { evl[126] = Ar[7].z; dvl[127] = Ar[7].w; }
  if (t == 0) evl[127] = 0.0f;
  __syncthreads();
  if (t < 128) {
    dvec_g[bb * 128 + t] = dvl[t];
    evec_g[bb * 128 + t] = evl[t];
  }
}

// ============================ K8: Sturm multisection eigenvalues ============================
// r15: 16-way multisection (17x shrink/sweep, 8 sweeps ~ 7e9 > fp32 res).
// 2 blocks/batch (64 eigenvalues each) -> grid 32. (d[ii], e2[ii-1]) packed
// into one float2 LDS array; recurrence software-pipelined DEPTH-2 so the
// b64 broadcast load is off the dependent q-chain. Parallel Gershgorin.
__global__ __launch_bounds__(1024, 1) void k_bisect(const float* __restrict__ dvec_g,
                                                    const float* __restrict__ evec_g,
                                                    float* __restrict__ lam_g) {
  const int bb = blockIdx.x >> 1, half = blockIdx.x & 1;
  const int t = threadIdx.x;
  const int idx = half * 64 + (t >> 4);  // eigenvalue index this thread solves
  const int c = t & 15;                  // candidate slot 0..15
  __shared__ __align__(8) float2 de[130];  // de[ii] = (d[ii], e2[ii-1])
  __shared__ float eabs_s[128];
  __shared__ float redlo[2], redhi[2];
  if (t < 128) {
    float d = dvec_g[bb * 128 + t];
    float e = evec_g[bb * 128 + t];      // offdiag (t,t+1); e[127]=0
    de[t].x = d;
    de[t + 1].y = e * e;
    eabs_s[t] = fabsf(e);
    if (t == 0) {
      de[0].y = 0.f;
      de[128].x = 0.f;
      de[129] = make_float2(0.f, 0.f);
    }
  }
  __syncthreads();
  // ---- parallel Gershgorin bounds
  if (t < 128) {
    float d = de[t].x;
    float r = ((t > 0) ? eabs_s[t - 1] : 0.f) + ((t < 127) ? eabs_s[t] : 0.f);
    float lo_t = d - r, hi_t = d + r;
    for (int s = 32; s > 0; s >>= 1) {
      lo_t = fminf(lo_t, __shfl_xor(lo_t, s));
      hi_t = fmaxf(hi_t, __shfl_xor(hi_t, s));
    }
    if ((t & 63) == 0) { redlo[t >> 6] = lo_t; redhi[t >> 6] = hi_t; }
  }
  __syncthreads();
  float lo = fminf(redlo[0], redlo[1]);
  float hi = fmaxf(redhi[0], redhi[1]);
  const float frac = (float)(c + 1) * (1.0f / 17.0f);
  for (int it = 0; it < 8; ++it) {
    float mid = lo + (hi - lo) * frac;
    float q = de[0].x - mid;
    int cnt = (q < 0.0f) ? 1 : 0;
    float2 c0v = de[1], c1v = de[2];   // depth-2 pipeline
    #pragma unroll 2
    for (int ii = 1; ii < 128; ++ii) {
      float2 nx = de[ii + 2];          // issued ahead of the q-chain
      float denom = q;
      if (fabsf(denom) < 1e-25f) denom = (denom < 0.0f) ? -1e-25f : 1e-25f;
      q = (c0v.x - mid) - __fdividef(c0v.y, denom);
      cnt += (q < 0.0f) ? 1 : 0;
      c0v = c1v; c1v = nx;
    }
    bool isLo = (cnt <= idx);
    float cl = isLo ? mid : -1e30f;
    float ch = isLo ? 1e30f : mid;
    #pragma unroll
    for (int s = 1; s < 16; s <<= 1) {
      cl = fmaxf(cl, __shfl_xor(cl, s));
      ch = fminf(ch, __shfl_xor(ch, s));
    }
    lo = fmaxf(lo, cl);
    hi = fminf(hi, ch);
  }
  if (c == 0) lam_g[bb * 128 + idx] = 0.5f * (lo + hi);
}

// ============================ K8b: clamp + normalize ============================
__global__ __launch_bounds__(128) void k_dist(const float* __restrict__ lam_g,
                                              float* __restrict__ dist_out) {
  const int bb = blockIdx.x, t = threadIdx.x;
  __shared__ float rr[2];
  float evc = fmaxf(lam_g[bb * 128 + t], 1e-12f);
  float ssum = evc;
  for (int s = 32; s > 0; s >>= 1) ssum += __shfl_xor(ssum, s);
  if ((t & 63) == 0) rr[t >> 6] = ssum;
  __syncthreads();
  float tot = rr[0] + rr[1];
  dist_out[bb * 128 + t] = evc / tot;
}

// ============================ launch ============================
extern "C" void kernel_launch(void* const* d_in, const int* in_sizes, int n_in,
                              void* d_out, int out_size, void* d_ws, size_t ws_size,
                              hipStream_t stream) {
  const float* x      = (const float*)d_in[0];
  const float* L      = (const float*)d_in[1];
  const float* temp_p = (const float*)d_in[2];
  const float* tgt_p  = (const float*)d_in[3];
  const float* step_p = (const float*)d_in[4];
  float* out = (float*)d_out;
  float* ws  = (float*)d_ws;

  float* bases = ws;                    // 2097152
  float* G     = bases + 2097152;       // 16384
  float* w     = G + 16384;             // 16384
  float* s0    = w + 16384;             // 262144
  float* s1    = s0 + 262144;           // 262144
  float* n0    = s1 + 262144;           // 2048
  float* n1    = n0 + 2048;             // 2048
  float* dv    = n1 + 2048;             // 2048
  float* ev    = dv + 2048;             // 2048
  float* lamg  = ev + 2048;             // 2048

  // gram partials: reuse s0..s1 span (32 x 16384 = 524288 floats). k_meas
  // is the first writer of s0 and runs after k_gsum -- no lifetime overlap.
  float* gpart = s0;

  float* o_avg  = out;                  // 2048
  float* o_dist = out + 2048;           // 2048
  float* o_rho  = out + 4096;           // 262144
  float* o_meas = out + 266240;         // 262144
  float* o_eq   = out + 528384;         // 262144
  float* o_expr = out + 790528;         // 262144
  float* o_ten  = out + 1052672;        // 16384

  hipFuncSetAttribute((const void*)k_cayley,
                      hipFuncAttributeMaxDynamicSharedMemorySize, 67584);
  hipFuncSetAttribute((const void*)k_step,
                      hipFuncAttributeMaxDynamicSharedMemorySize, 66064);

  k_cayley<<<128, 512, 67584, stream>>>(L, bases);
  k_gramp<<<32, 256, 0, stream>>>(bases, gpart);
  k_gsum<<<64, 256, 0, stream>>>(gpart, G);
  k_wsoft<<<128, 128, 0, stream>>>(G, temp_p, w, o_ten);
  k_meas<<<128, 128, 0, stream>>>(x, bases, o_meas, s0, n0);
  k_step<<<2048, 128, 66064, stream>>>(s0, s1, w, n0, n1, tgt_p, step_p);
  k_step<<<2048, 128, 66064, stream>>>(s1, s0, w, n1, n0, tgt_p, step_p);
  k_step<<<2048, 128, 66064, stream>>>(s0, s1, w, n0, n1, tgt_p, step_p);
  k_step<<<2048, 128, 66064, stream>>>(s1, s0, w, n1, n0, tgt_p, step_p);
  k_step<<<2048, 128, 66064, stream>>>(s0, o_eq, w, n0, n1, tgt_p, step_p);
  k_expr<<<128, 128, 0, stream>>>(o_eq, bases, o_expr);
  k_avg<<<16, 128, 0, stream>>>(o_expr, o_avg);
  k_rho<<<128, 256, 0, stream>>>(o_eq, n1, o_rho);
  k_tridiag<<<16, 512, 0, stream>>>(o_rho, dv, ev);
  k_bisect<<<32, 1024, 0, stream>>>(dv, ev, lamg);
  k_dist<<<16, 128, 0, stream>>>(lamg, o_dist);
}

// Round 19
// 788.669 us; speedup vs baseline: 1.2434x; 1.2434x over previous
//
#include <hip/hip_runtime.h>

// Problem constants: BATCH=16, N=128, D=128, N_STEPS=5, EPS=1e-10
#define EPSF 1e-10f

__device__ __forceinline__ float f4sel(float4 a, int cc) {
  float r = (cc == 0) ? a.x : a.y;
  r = (cc == 2) ? a.z : r;
  r = (cc == 3) ? a.w : r;
  return r;
}

__device__ __forceinline__ float dpp_quad_sum(float x) {
  // full sum within each 4-lane quad: quad_perm [1,0,3,2] then [2,3,0,1]
  x += __int_as_float(__builtin_amdgcn_update_dpp(
      0, __float_as_int(x), 0xB1, 0xf, 0xf, true));
  x += __int_as_float(__builtin_amdgcn_update_dpp(
      0, __float_as_int(x), 0x4E, 0xf, 0xf, true));
  return x;
}

__device__ __forceinline__ float dpp_red_sum64(float x) {
  // canonical GCN wave64 sum: accumulate into lane 63, broadcast via readlane
  x += __int_as_float(__builtin_amdgcn_update_dpp(0, __float_as_int(x), 0x111, 0xf, 0xf, true));
  x += __int_as_float(__builtin_amdgcn_update_dpp(0, __float_as_int(x), 0x112, 0xf, 0xf, true));
  x += __int_as_float(__builtin_amdgcn_update_dpp(0, __float_as_int(x), 0x114, 0xf, 0xe, true));
  x += __int_as_float(__builtin_amdgcn_update_dpp(0, __float_as_int(x), 0x118, 0xf, 0xc, true));
  x += __int_as_float(__builtin_amdgcn_update_dpp(0, __float_as_int(x), 0x142, 0xa, 0xf, true));
  x += __int_as_float(__builtin_amdgcn_update_dpp(0, __float_as_int(x), 0x143, 0xc, 0xf, true));
  return __int_as_float(__builtin_amdgcn_readlane(__float_as_int(x), 63));
}

// ============================ K1: Cayley bases ============================
// M = I + A, A = L - L^T (symmetric part = I, SPD => unpivoted GJ stable).
// U = 2*M^{-1} - I. A IN REGISTERS (r9); one barrier/step via ping-pong
// rowbuf/colbuf publications.
#define SWZ4(i, j4) ((i) * 32 + ((j4) ^ ((i) & 31)))
#define SWZF(i, j) (SWZ4((i), (j) >> 2) * 4 + ((j) & 3))

__global__ __launch_bounds__(512, 2) void k_cayley(const float* __restrict__ L,
                                                   float* __restrict__ bases) {
  extern __shared__ float4 sm4[];
  float4* M4  = sm4;                   // 4096 f4 = 64 KB
  float*  Mf  = (float*)M4;
  float4* rb0 = sm4 + 4096;            // rowbuf ping (32 f4)
  float4* rb1 = rb0 + 32;              // rowbuf pong
  float*  cb0 = (float*)(rb1 + 32);    // colbuf ping (128 f)
  float*  cb1 = cb0 + 128;             // colbuf pong
  const int n = blockIdx.x, t = threadIdx.x;
  const float* Ln = L + n * 16384;
  // load linear -> swizzled (coalesced global reads)
  for (int f = t; f < 4096; f += 512) {
    int i = f >> 5, j4 = f & 31;
    M4[SWZ4(i, j4)] = ((const float4*)Ln)[f];
  }
  __syncthreads();
  // antisymmetrize in place + unit diagonal
  for (int f = t; f < 16384; f += 512) {
    int i = f >> 7, j = f & 127;
    if (i < j) {
      int a = SWZF(i, j), b = SWZF(j, i);
      float va = Mf[a], vb = Mf[b];
      Mf[a] = va - vb;
      Mf[b] = vb - va;
    } else if (i == j) {
      Mf[SWZF(i, i)] = 1.0f;
    }
  }
  __syncthreads();
  const int i = t & 127;     // row owned by this thread
  const int h2 = t >> 7;     // which 8-f4 chunk of the row (0..3)
  // ---- pull own row slice into registers
  float4 Ar[8];
  #pragma unroll
  for (int u = 0; u < 8; ++u) Ar[u] = M4[SWZ4(i, h2 * 8 + u)];
  // ---- prologue publishes: row 0, column 0
  if (i == 0) {
    #pragma unroll
    for (int u = 0; u < 8; ++u) rb0[h2 * 8 + u] = Ar[u];
  }
  if (h2 == 0) cb0[i] = Ar[0].x;   // element (i, 0)
  __syncthreads();
  for (int k = 0; k < 128; ++k) {
    const float4* rbC = (k & 1) ? rb1 : rb0;
    float4*       rbN = (k & 1) ? rb0 : rb1;
    const float*  cbC = (k & 1) ? cb1 : cb0;
    float*        cbN = (k & 1) ? cb0 : cb1;
    const float pivinv = 1.0f / cbC[k];   // broadcast
    const float coef = cbC[i] * pivinv;   // own multiplier (coalesced)
    const int kj4 = k >> 2, kc = k & 3;
    const int nj4 = (k + 1) >> 2, ncc = (k + 1) & 3;
    const bool isPiv = (i == k);
    const bool isNext = (i == k + 1);
    float colv = 0.0f;
    #pragma unroll
    for (int u = 0; u < 8; ++u) {
      const int jj = h2 * 8 + u;
      float4 r = rbC[jj];   // broadcast read (uniform per wave)
      float4 a;
      if (isPiv) {          // scale pivot row; (k,k) -> pivinv
        a.x = r.x * pivinv; a.y = r.y * pivinv;
        a.z = r.z * pivinv; a.w = r.w * pivinv;
        if (jj == kj4) {
          a.x = (kc == 0) ? pivinv : a.x;
          a.y = (kc == 1) ? pivinv : a.y;
          a.z = (kc == 2) ? pivinv : a.z;
          a.w = (kc == 3) ? pivinv : a.w;
        }
      } else {              // eliminate; (i,k) -> -coef
        a = Ar[u];
        a.x -= coef * r.x; a.y -= coef * r.y;
        a.z -= coef * r.z; a.w -= coef * r.w;
        if (jj == kj4) {
          a.x = (kc == 0) ? -coef : a.x;
          a.y = (kc == 1) ? -coef : a.y;
          a.z = (kc == 2) ? -coef : a.z;
          a.w = (kc == 3) ? -coef : a.w;
        }
      }
      Ar[u] = a;
      if (jj == nj4) colv = f4sel(a, ncc);  // extract A[i][k+1]
      if (isNext) rbN[jj] = a;              // publish next pivot row
    }
    if (h2 == (nj4 >> 3)) cbN[i] = colv;    // publish next column (k<127)
    __syncthreads();
  }
  // ---- regs -> LDS, then U = 2*Minv - I coalesced writeout
  #pragma unroll
  for (int u = 0; u < 8; ++u) M4[SWZ4(i, h2 * 8 + u)] = Ar[u];
  __syncthreads();
  for (int f = t; f < 16384; f += 512) {
    int ii = f >> 7, j = f & 127;
    float v = Mf[SWZF(ii, j)];
    bases[n * 16384 + f] = 2.0f * v - ((ii == j) ? 1.0f : 0.0f);
  }
}

// ============================ K2a: Gram = B_flat B_flat^T (two-stage GEMM) ============================
__global__ __launch_bounds__(256) void k_gramp(const float* __restrict__ bases,
                                               float* __restrict__ part) {
  __shared__ __align__(16) float tile[64][132];
  const int b = blockIdx.x, t = threadIdx.x;
  const int tx = t & 15, ty = t >> 4;
  const int i0 = tx * 8, j0 = ty * 8;
  const int k0 = b * 512;
  float acc[8][8];
  #pragma unroll
  for (int u = 0; u < 8; ++u)
    #pragma unroll
    for (int v = 0; v < 8; ++v) acc[u][v] = 0.f;
  for (int c0 = 0; c0 < 512; c0 += 64) {
    __syncthreads();  // protect previous sub-chunk's reads
    for (int f = t; f < 8192; f += 256) {
      int i = f >> 6, kk = f & 63;
      tile[kk][i] = bases[i * 16384 + k0 + c0 + kk];
    }
    __syncthreads();
    for (int kk = 0; kk < 64; ++kk) {
      float4 a0 = *(const float4*)&tile[kk][i0];
      float4 a1 = *(const float4*)&tile[kk][i0 + 4];
      float4 b0 = *(const float4*)&tile[kk][j0];
      float4 b1 = *(const float4*)&tile[kk][j0 + 4];
      float av[8] = {a0.x, a0.y, a0.z, a0.w, a1.x, a1.y, a1.z, a1.w};
      float bv[8] = {b0.x, b0.y, b0.z, b0.w, b1.x, b1.y, b1.z, b1.w};
      #pragma unroll
      for (int u = 0; u < 8; ++u)
        #pragma unroll
        for (int v = 0; v < 8; ++v) acc[u][v] += av[u] * bv[v];
    }
  }
  float* P = part + b * 16384;
  #pragma unroll
  for (int u = 0; u < 8; ++u) {
    #pragma unroll
    for (int v4 = 0; v4 < 2; ++v4) {
      float4 o;
      o.x = acc[u][v4 * 4 + 0]; o.y = acc[u][v4 * 4 + 1];
      o.z = acc[u][v4 * 4 + 2]; o.w = acc[u][v4 * 4 + 3];
      *(float4*)&P[(i0 + u) * 128 + j0 + v4 * 4] = o;
    }
  }
}

// Stage 2: deterministic partial reduction (no atomics).
__global__ __launch_bounds__(256) void k_gsum(const float* __restrict__ part,
                                              float* __restrict__ G) {
  const int g = blockIdx.x * 256 + threadIdx.x;
  float s = 0.f;
  for (int p = 0; p < 32; ++p) s += part[p * 16384 + g];
  G[g] = s;
}

// ============================ K2b: tension + softmax + mask ============================
__global__ __launch_bounds__(128) void k_wsoft(const float* __restrict__ G,
                                               const float* __restrict__ temp_p,
                                               float* __restrict__ w,
                                               float* __restrict__ tension_out) {
  const int i = blockIdx.x, t = threadIdx.x;  // t = j
  __shared__ float rr[2], r2[2];
  float temp = fmaxf(fabsf(*temp_p), 0.01f);
  float gii = G[i * 128 + i], gjj = G[t * 128 + t], gij = G[i * 128 + t];
  float ten = sqrtf(fmaxf(gii + gjj - 2.0f * gij, 0.0f) + 1e-8f);
  tension_out[i * 128 + t] = ten;
  float logit = -ten / temp;
  float m = logit;
  for (int s = 32; s > 0; s >>= 1) m = fmaxf(m, __shfl_xor(m, s));
  if ((t & 63) == 0) rr[t >> 6] = m;
  __syncthreads();
  float mx = fmaxf(rr[0], rr[1]);
  float ex = expf(logit - mx);
  float ssum = ex;
  for (int s = 32; s > 0; s >>= 1) ssum += __shfl_xor(ssum, s);
  if ((t & 63) == 0) r2[t >> 6] = ssum;
  __syncthreads();
  float tot = r2[0] + r2[1];
  float wv = ex / tot;
  if (t == i) wv = 0.0f;
  w[i * 128 + t] = wv;
}

// ============================ K3: measurements + initial norms ============================
__global__ __launch_bounds__(128) void k_meas(const float* __restrict__ x,
                                              const float* __restrict__ bases,
                                              float* __restrict__ meas_out,
                                              float* __restrict__ state0,
                                              float* __restrict__ norms0) {
  const int n = blockIdx.x, t = threadIdx.x;  // t = k
  __shared__ float xs[2048];
  __shared__ float red[2];
  for (int f = t; f < 2048; f += 128) xs[f] = x[f];
  __syncthreads();
  float acc[16];
  #pragma unroll
  for (int b = 0; b < 16; ++b) acc[b] = 0.f;
  for (int d = 0; d < 128; ++d) {
    float u = bases[n * 16384 + d * 128 + t];  // coalesced over t
    #pragma unroll
    for (int b = 0; b < 16; ++b) acc[b] += xs[b * 128 + d] * u;
  }
  for (int b = 0; b < 16; ++b) {
    meas_out[(b * 128 + n) * 128 + t] = acc[b];
    state0[(b * 128 + n) * 128 + t] = acc[b];
  }
  for (int b = 0; b < 16; ++b) {
    float v = acc[b] * acc[b];
    for (int s = 32; s > 0; s >>= 1) v += __shfl_down(v, s);
    if ((t & 63) == 0) red[t >> 6] = v;
    __syncthreads();
    if (t == 0) norms0[b * 128 + n] = sqrtf(red[0] + red[1]);
    __syncthreads();
  }
}

// ============================ K4: one interaction step ============================
// r14 champion (REVERTED from r17 full-stage: 66KB LDS -> 2 blocks/CU and
// 32x global re-read traffic regressed it). Chunked staging, norm-identity
// distance, float4 staging.
__global__ __launch_bounds__(128) void k_step(const float* __restrict__ src,
                                              float* __restrict__ dst,
                                              const float* __restrict__ w,
                                              const float* __restrict__ norms_in,
                                              float* __restrict__ norms_out,
                                              const float* __restrict__ tgt_p,
                                              const float* __restrict__ step_p) {
  const int b = blockIdx.x >> 7, n = blockIdx.x & 127, t = threadIdx.x;
  __shared__ float sn[128];
  __shared__ __align__(16) float chunk[32][132];
  __shared__ float red[2][32];
  __shared__ float cbuf[32];
  __shared__ float red2[2];
  const float target = *tgt_p;
  const float step = fminf(fmaxf(fabsf(*step_p), 0.001f), 0.5f);
  const float* srcb = src + b * 16384;
  float x_d = srcb[n * 128 + t];
  sn[t] = x_d;
  float norm_n = norms_in[b * 128 + n];
  float nn2 = norm_n * norm_n;
  float f_d = 0.0f;
  __syncthreads();
  for (int c0 = 0; c0 < 128; c0 += 32) {
    // float4 staging: 1024 f4 per chunk, 8 per thread, coalesced 16B/lane
    for (int f = t; f < 1024; f += 128) {
      int row = f >> 5, c4 = f & 31;
      ((float4*)&chunk[row][0])[c4] =
          ((const float4*)(srcb + (c0 + row) * 128))[c4];
    }
    __syncthreads();
    int m = t & 31, q = t >> 5;
    float dp = 0.f;
    const float* cr = &chunk[m][0];
    #pragma unroll
    for (int i2 = 0; i2 < 32; ++i2) {
      int dd = q * 32 + i2;
      dp += cr[dd] * sn[dd];
    }
    dp += __shfl_xor(dp, 32);
    int wave = t >> 6;
    if ((t & 63) < 32) red[wave][m] = dp;
    __syncthreads();
    if (t < 32) {
      float dot = red[0][t] + red[1][t];
      int mm = c0 + t;
      float norm_m = norms_in[b * 128 + mm];
      float sq = nn2 + norm_m * norm_m - 2.0f * dot;
      float wnm = w[n * 128 + mm];
      float cs = dot / ((norm_n + EPSF) * (norm_m + EPSF));
      float fm = (cs - target) * wnm;
      cbuf[t] = fm / (sqrtf(fmaxf(sq, 0.0f)) + EPSF);
    }
    __syncthreads();
    #pragma unroll
    for (int mi = 0; mi < 32; ++mi) f_d += cbuf[mi] * (x_d - chunk[mi][t]);
    __syncthreads();
  }
  float nv = x_d + step * f_d;
  dst[(b * 128 + n) * 128 + t] = nv;
  float v = nv * nv;
  for (int s = 32; s > 0; s >>= 1) v += __shfl_down(v, s);
  if ((t & 63) == 0) red2[t >> 6] = v;
  __syncthreads();
  if (t == 0) norms_out[b * 128 + n] = sqrtf(red2[0] + red2[1]);
}

// ============================ K5: expressions ============================
__global__ __launch_bounds__(128) void k_expr(const float* __restrict__ eq,
                                              const float* __restrict__ bases,
                                              float* __restrict__ expr_out) {
  const int n = blockIdx.x, t = threadIdx.x;  // t = k
  __shared__ __align__(16) float es[16][128];
  for (int f = t; f < 2048; f += 128)
    es[f >> 7][f & 127] = eq[((f >> 7) * 128 + n) * 128 + (f & 127)];
  __syncthreads();
  float acc[16];
  #pragma unroll
  for (int b = 0; b < 16; ++b) acc[b] = 0.f;
  const float4* U = (const float4*)(bases + n * 16384 + t * 128);
  for (int d4 = 0; d4 < 32; ++d4) {
    float4 u = U[d4];
    #pragma unroll
    for (int b = 0; b < 16; ++b) {
      float4 e4 = ((const float4*)&es[b][0])[d4];
      acc[b] += u.x * e4.x + u.y * e4.y + u.z * e4.z + u.w * e4.w;
    }
  }
  for (int b = 0; b < 16; ++b) expr_out[(b * 128 + n) * 128 + t] = acc[b];
}

// ============================ K5b: output_avg ============================
__global__ __launch_bounds__(128) void k_avg(const float* __restrict__ expr,
                                             float* __restrict__ avg) {
  const int b = blockIdx.x, t = threadIdx.x;
  float s = 0.f;
  for (int n = 0; n < 128; ++n) s += expr[(b * 128 + n) * 128 + t];
  avg[b * 128 + t] = s * (1.0f / 128.0f);
}

// ============================ K6: rho ============================
__global__ __launch_bounds__(256) void k_rho(const float* __restrict__ eq,
                                             const float* __restrict__ norms,
                                             float* __restrict__ rho) {
  const int b = blockIdx.x >> 3, dt = blockIdx.x & 7;
  const int t = threadIdx.x;
  __shared__ float ch[32][129];
  int e = t & 127, dl = t >> 7;
  float acc[8];
  #pragma unroll
  for (int o = 0; o < 8; ++o) acc[o] = 0.f;
  for (int c0 = 0; c0 < 128; c0 += 32) {
    for (int f = t; f < 4096; f += 256) {
      int row = f >> 7, col = f & 127;
      int nn = c0 + row;
      float inv = 1.0f / (norms[b * 128 + nn] + EPSF);
      ch[row][col] = eq[(b * 128 + nn) * 128 + col] * inv;
    }
    __syncthreads();
    for (int nn = 0; nn < 32; ++nn) {
      float me = ch[nn][e];
      #pragma unroll
      for (int o = 0; o < 8; ++o) {
        int d = dt * 16 + dl + o * 2;
        acc[o] += ch[nn][d] * me;
      }
    }
    __syncthreads();
  }
  for (int o = 0; o < 8; ++o) {
    int d = dt * 16 + dl + o * 2;
    rho[(b * 128 + d) * 128 + e] = acc[o] * (1.0f / 128.0f);
  }
}

// ============================ K7: Householder tridiagonalization ============================
// r14 champion (215 us). 8 waves, quarter-rows of 8 f4 in regs, DPP
// reductions, ping-pong column buffer, 2 barriers/step. AT STRUCTURAL FLOOR:
// r12 (regs+2w), r16 (replication) both regressed. Do not tune further.
__global__ __launch_bounds__(512, 1) void k_tridiag(const float* __restrict__ rho,
                                                    float* __restrict__ dvec_g,
                                                    float* __restrict__ evec_g) {
  __shared__ __align__(16) float cb0[128];
  __shared__ __align__(16) float cb1[128];
  __shared__ __align__(16) float pbuf[128];
  __shared__ float dvl[128], evl[128];
  __shared__ float redS[8], redK[8], redX[1];
  const int bb = blockIdx.x, t = threadIdx.x;
  const int i = t >> 2, h = t & 3, wv = t >> 6;
  const float* R = rho + bb * 16384;
  // ---- own quarter-row into registers (8 f4)
  float4 Ar[8];
  const float4* Rp = (const float4*)(R + i * 128 + h * 32);
  #pragma unroll
  for (int u = 0; u < 8; ++u) Ar[u] = Rp[u];
  // ---- prologue: column 0, sigma^2, x0, diag
  if (h == 0) {
    cb0[i] = (i == 0) ? 0.f : Ar[0].x;   // zeros at i<=k
    if (i == 0) dvl[0] = Ar[0].x;
    if (i == 1) redX[0] = Ar[0].x;
  }
  {
    float s2w = dpp_red_sum64((h == 0 && i > 0) ? Ar[0].x * Ar[0].x : 0.f);
    if ((t & 63) == 0) redS[wv] = s2w;
  }
  __syncthreads();
  for (int k = 0; k < 126; ++k) {
    const float* cbC = (k & 1) ? cb1 : cb0;   // column k (zeros at i<=k)
    float*       cbN = (k & 1) ? cb0 : cb1;   // column k+1
    // ---- uniform head
    float sig2 = redS[0] + redS[1] + redS[2] + redS[3] +
                 redS[4] + redS[5] + redS[6] + redS[7];
    float x0 = redX[0];
    const bool skip = (sig2 < 1e-30f);
    float sig = sqrtf(sig2);
    float alpha = (x0 >= 0.f) ? -sig : sig;
    if (skip) alpha = 0.f;
    float beta = skip ? 0.f : 1.f / (sig2 - alpha * x0);
    float w0 = x0 - alpha;
    if (t == 0) evl[k] = alpha;
    const int jn4 = (k + 1) >> 2, ncc = (k + 1) & 3, hn = (k + 1) >> 5;
    float vt = (i == k + 1) ? w0 : cbC[i];    // zeros for i<=k from buffer
    // ---- matvec p_i = beta * sum_j A[i][j] v[j] (quarter-split)
    const float4* cv4 = (const float4*)cbC;
    float pp = 0.f;
    #pragma unroll
    for (int u = 0; u < 8; ++u) {
      const int jj = h * 8 + u;
      float4 v = cv4[jj];
      if (jj == jn4) {
        v.x = (0 == ncc) ? w0 : v.x;
        v.y = (1 == ncc) ? w0 : v.y;
        v.z = (2 == ncc) ? w0 : v.z;
        v.w = (3 == ncc) ? w0 : v.w;
      }
      pp += Ar[u].x * v.x + Ar[u].y * v.y + Ar[u].z * v.z + Ar[u].w * v.w;
    }
    pp = dpp_quad_sum(pp);   // all 4 quarter-lanes hold the full row-dot
    float p = beta * pp;
    if (i <= k) p = 0.f;
    if (h == 0) pbuf[i] = p;
    float kpw = dpp_red_sum64((h == 0) ? vt * p : 0.f);
    if ((t & 63) == 0) redK[wv] = kpw;
    __syncthreads();  // S1: pbuf + redK visible
    float K = (redK[0] + redK[1] + redK[2] + redK[3] +
               redK[4] + redK[5] + redK[6] + redK[7]) * beta * 0.5f;
    // ---- rank-2 update in registers + extract column k+1
    float cn = 0.f;
    if (i > k) {
      float qt = p - K * vt;
      const float4* pv4 = (const float4*)pbuf;
      #pragma unroll
      for (int u = 0; u < 8; ++u) {
        const int jj = h * 8 + u;
        float4 v = cv4[jj];
        if (jj == jn4) {
          v.x = (0 == ncc) ? w0 : v.x;
          v.y = (1 == ncc) ? w0 : v.y;
          v.z = (2 == ncc) ? w0 : v.z;
          v.w = (3 == ncc) ? w0 : v.w;
        }
        float4 pq = pv4[jj];
        float qx = pq.x - K * v.x, qy = pq.y - K * v.y;
        float qz = pq.z - K * v.z, qw = pq.w - K * v.w;
        Ar[u].x -= vt * qx + qt * v.x;
        Ar[u].y -= vt * qy + qt * v.y;
        Ar[u].z -= vt * qz + qt * v.z;
        Ar[u].w -= vt * qw + qt * v.w;
        if (jj == jn4) cn = f4sel(Ar[u], ncc);
      }
    }
    // ---- publish next-step state (quarter hn owns column k+1)
    if (h == hn) cbN[i] = (i <= k + 1) ? 0.f : cn;
    if (i == k + 1 && h == hn) dvl[k + 1] = cn;
    if (i == k + 2 && h == hn) redX[0] = cn;
    float s2w = dpp_red_sum64((h == hn && i > k + 1) ? cn * cn : 0.f);
    if ((t & 63) == 0) redS[wv] = s2w;
    __syncthreads();  // S2
  }
  // ---- epilogue from registers
  if (i == 126 && h == 3) dvl[126] = Ar[7].z;
  if (i == 127 && h == 3) { evl[126] = Ar[7].z; dvl[127] = Ar[7].w; }
  if (t == 0) evl[127] = 0.0f;
  __syncthreads();
  if (t < 128) {
    dvec_g[bb * 128 + t] = dvl[t];
    evec_g[bb * 128 + t] = evl[t];
  }
}

// ============================ K8: Sturm multisection eigenvalues ============================
// r15: 16-way multisection (17x shrink/sweep, 8 sweeps ~ 7e9 > fp32 res).
// 2 blocks/batch (64 eigenvalues each) -> grid 32. (d[ii], e2[ii-1]) packed
// into one float2 LDS array; recurrence software-pipelined DEPTH-2 so the
// b64 broadcast load is off the dependent q-chain. Parallel Gershgorin.
__global__ __launch_bounds__(1024, 1) void k_bisect(const float* __restrict__ dvec_g,
                                                    const float* __restrict__ evec_g,
                                                    float* __restrict__ lam_g) {
  const int bb = blockIdx.x >> 1, half = blockIdx.x & 1;
  const int t = threadIdx.x;
  const int idx = half * 64 + (t >> 4);  // eigenvalue index this thread solves
  const int c = t & 15;                  // candidate slot 0..15
  __shared__ __align__(8) float2 de[130];  // de[ii] = (d[ii], e2[ii-1])
  __shared__ float eabs_s[128];
  __shared__ float redlo[2], redhi[2];
  if (t < 128) {
    float d = dvec_g[bb * 128 + t];
    float e = evec_g[bb * 128 + t];      // offdiag (t,t+1); e[127]=0
    de[t].x = d;
    de[t + 1].y = e * e;
    eabs_s[t] = fabsf(e);
    if (t == 0) {
      de[0].y = 0.f;
      de[128].x = 0.f;
      de[129] = make_float2(0.f, 0.f);
    }
  }
  __syncthreads();
  // ---- parallel Gershgorin bounds
  if (t < 128) {
    float d = de[t].x;
    float r = ((t > 0) ? eabs_s[t - 1] : 0.f) + ((t < 127) ? eabs_s[t] : 0.f);
    float lo_t = d - r, hi_t = d + r;
    for (int s = 32; s > 0; s >>= 1) {
      lo_t = fminf(lo_t, __shfl_xor(lo_t, s));
      hi_t = fmaxf(hi_t, __shfl_xor(hi_t, s));
    }
    if ((t & 63) == 0) { redlo[t >> 6] = lo_t; redhi[t >> 6] = hi_t; }
  }
  __syncthreads();
  float lo = fminf(redlo[0], redlo[1]);
  float hi = fmaxf(redhi[0], redhi[1]);
  const float frac = (float)(c + 1) * (1.0f / 17.0f);
  for (int it = 0; it < 8; ++it) {
    float mid = lo + (hi - lo) * frac;
    float q = de[0].x - mid;
    int cnt = (q < 0.0f) ? 1 : 0;
    float2 c0v = de[1], c1v = de[2];   // depth-2 pipeline
    #pragma unroll 2
    for (int ii = 1; ii < 128; ++ii) {
      float2 nx = de[ii + 2];          // issued ahead of the q-chain
      float denom = q;
      if (fabsf(denom) < 1e-25f) denom = (denom < 0.0f) ? -1e-25f : 1e-25f;
      q = (c0v.x - mid) - __fdividef(c0v.y, denom);
      cnt += (q < 0.0f) ? 1 : 0;
      c0v = c1v; c1v = nx;
    }
    bool isLo = (cnt <= idx);
    float cl = isLo ? mid : -1e30f;
    float ch = isLo ? 1e30f : mid;
    #pragma unroll
    for (int s = 1; s < 16; s <<= 1) {
      cl = fmaxf(cl, __shfl_xor(cl, s));
      ch = fminf(ch, __shfl_xor(ch, s));
    }
    lo = fmaxf(lo, cl);
    hi = fminf(hi, ch);
  }
  if (c == 0) lam_g[bb * 128 + idx] = 0.5f * (lo + hi);
}

// ============================ K8b: clamp + normalize ============================
__global__ __launch_bounds__(128) void k_dist(const float* __restrict__ lam_g,
                                              float* __restrict__ dist_out) {
  const int bb = blockIdx.x, t = threadIdx.x;
  __shared__ float rr[2];
  float evc = fmaxf(lam_g[bb * 128 + t], 1e-12f);
  float ssum = evc;
  for (int s = 32; s > 0; s >>= 1) ssum += __shfl_xor(ssum, s);
  if ((t & 63) == 0) rr[t >> 6] = ssum;
  __syncthreads();
  float tot = rr[0] + rr[1];
  dist_out[bb * 128 + t] = evc / tot;
}

// ============================ launch ============================
extern "C" void kernel_launch(void* const* d_in, const int* in_sizes, int n_in,
                              void* d_out, int out_size, void* d_ws, size_t ws_size,
                              hipStream_t stream) {
  const float* x      = (const float*)d_in[0];
  const float* L      = (const float*)d_in[1];
  const float* temp_p = (const float*)d_in[2];
  const float* tgt_p  = (const float*)d_in[3];
  const float* step_p = (const float*)d_in[4];
  float* out = (float*)d_out;
  float* ws  = (float*)d_ws;

  float* bases = ws;                    // 2097152
  float* G     = bases + 2097152;       // 16384
  float* w     = G + 16384;             // 16384
  float* s0    = w + 16384;             // 262144
  float* s1    = s0 + 262144;           // 262144
  float* n0    = s1 + 262144;           // 2048
  float* n1    = n0 + 2048;             // 2048
  float* dv    = n1 + 2048;             // 2048
  float* ev    = dv + 2048;             // 2048
  float* lamg  = ev + 2048;             // 2048

  // gram partials: reuse s0..s1 span (32 x 16384 = 524288 floats). k_meas
  // is the first writer of s0 and runs after k_gsum -- no lifetime overlap.
  float* gpart = s0;

  float* o_avg  = out;                  // 2048
  float* o_dist = out + 2048;           // 2048
  float* o_rho  = out + 4096;           // 262144
  float* o_meas = out + 266240;         // 262144
  float* o_eq   = out + 528384;         // 262144
  float* o_expr = out + 790528;         // 262144
  float* o_ten  = out + 1052672;        // 16384

  hipFuncSetAttribute((const void*)k_cayley,
                      hipFuncAttributeMaxDynamicSharedMemorySize, 67584);

  k_cayley<<<128, 512, 67584, stream>>>(L, bases);
  k_gramp<<<32, 256, 0, stream>>>(bases, gpart);
  k_gsum<<<64, 256, 0, stream>>>(gpart, G);
  k_wsoft<<<128, 128, 0, stream>>>(G, temp_p, w, o_ten);
  k_meas<<<128, 128, 0, stream>>>(x, bases, o_meas, s0, n0);
  k_step<<<2048, 128, 0, stream>>>(s0, s1, w, n0, n1, tgt_p, step_p);
  k_step<<<2048, 128, 0, stream>>>(s1, s0, w, n1, n0, tgt_p, step_p);
  k_step<<<2048, 128, 0, stream>>>(s0, s1, w, n0, n1, tgt_p, step_p);
  k_step<<<2048, 128, 0, stream>>>(s1, s0, w, n1, n0, tgt_p, step_p);
  k_step<<<2048, 128, 0, stream>>>(s0, o_eq, w, n0, n1, tgt_p, step_p);
  k_expr<<<128, 128, 0, stream>>>(o_eq, bases, o_expr);
  k_avg<<<16, 128, 0, stream>>>(o_expr, o_avg);
  k_rho<<<128, 256, 0, stream>>>(o_eq, n1, o_rho);
  k_tridiag<<<16, 512, 0, stream>>>(o_rho, dv, ev);
  k_bisect<<<32, 1024, 0, stream>>>(dv, ev, lamg);
  k_dist<<<16, 128, 0, stream>>>(lamg, o_dist);
}